// Round 3
// baseline (75.182 us; speedup 1.0000x reference)
//
#include <hip/hip_runtime.h>

#define BB 4
#define NN 4096
#define EE 1024
#define FIN 128
#define FOUT 128
#define FE 64
#define CAP 33        // max edges per node (Poisson mean 2.05)
#define LSTRIDE 34
#define CAPE 40       // max nodes per edge (Poisson mean 8.2)

#define GRID_LISTS (BB * NN / 4)    // 4096
#define GRID_HEPE  (BB * EE / 4)    // 1024
#define GRID_DINV  (BB * NN / 256)  // 64
#define GRID_GEMM  (BB * NN / 32)   // 512

typedef unsigned short u16;
typedef unsigned long long u64;

// ---------------- K_pre: fused {lists+escatter | hepe | dinv | gemm} ----------------
__global__ __launch_bounds__(256) void k_pre(const float* __restrict__ T,
                                             const float* __restrict__ edge,
                                             const float* __restrict__ ew,
                                             const float* __restrict__ D,
                                             const float* __restrict__ node,
                                             const float* __restrict__ W,
                                             float* __restrict__ hepe,
                                             float* __restrict__ dinv,
                                             u16* __restrict__ lists,
                                             int* __restrict__ ecnt,
                                             u16* __restrict__ elists,
                                             float* __restrict__ nodeW,
                                             int withGemm) {
    __shared__ float tile[32][FIN];
    int bid  = blockIdx.x;
    int t    = threadIdx.x;
    int lane = t & 63;
    int wid  = t >> 6;

    if (bid < GRID_LISTS) {
        // ---- per-node edge list from T, plus fused scatter into per-edge lists ----
        int row = bid * 4 + wid;                 // b*N + n
        int b = row >> 12, n = row & (NN - 1);
        const float4* rowT = (const float4*)(T + (size_t)row * EE);
        u16* L = lists + (size_t)row * LSTRIDE;
        int base = 0;
        int myE = -1;                            // this lane's edge (lane-th list entry)
#pragma unroll
        for (int i = 0; i < 4; i++) {
            float4 tv = rowT[i * 64 + lane];
            float vs[4] = {tv.x, tv.y, tv.z, tv.w};
            int c = (tv.x != 0.f) + (tv.y != 0.f) + (tv.z != 0.f) + (tv.w != 0.f);
            int x = c;
#pragma unroll
            for (int d = 1; d < 64; d <<= 1) {
                int o = __shfl_up(x, d, 64);
                if (lane >= d) x += o;
            }
            int tot = __shfl(x, 63, 64);
            int pos = base + x - c;
#pragma unroll
            for (int s = 0; s < 4; s++) {
                if (vs[s] != 0.f) {
                    if (pos < CAP) L[1 + pos] = (u16)((i * 64 + lane) * 4 + s);
                    pos++;
                }
            }
            base += tot;
        }
        int cn = base < CAP ? base : CAP;
        if (lane == 0) L[0] = (u16)cn;
        // gather my entry back (written by possibly another lane) via LDS-free reread
        if (lane < cn) myE = L[1 + lane];        // L is in L2, just-written
        if (myE >= 0) {
            int eb = (b << 10) + myE;
            int pos = atomicAdd(&ecnt[eb], 1);
            if (pos < CAPE) elists[(size_t)eb * CAPE + pos] = (u16)n;
        }
    } else if (bid < GRID_LISTS + GRID_HEPE) {
        // ---- HePe[b,e] = dot(edge[b,e,:], edge_weight) ----
        int row = (bid - GRID_LISTS) * 4 + wid;  // b*E + e
        float v = edge[(size_t)row * FE + lane] * ew[lane];
#pragma unroll
        for (int d = 32; d >= 1; d >>= 1) v += __shfl_xor(v, d, 64);
        if (lane == 0) hepe[row] = v;
    } else if (bid < GRID_LISTS + GRID_HEPE + GRID_DINV) {
        // ---- dinv[b,n] = 1/sqrt(D[b,n,n]) ----
        int idx = (bid - GRID_LISTS - GRID_HEPE) * 256 + t;  // b*N + n
        int b = idx >> 12, n = idx & (NN - 1);
        float v = D[((size_t)b * NN + n) * NN + n];
        dinv[idx] = (v != 0.0f) ? (1.0f / sqrtf(v)) : 0.0f;
    } else if (withGemm) {
        // ---- nodeW = node @ W (32 rows per block) ----
        size_t row0 = (size_t)(bid - GRID_LISTS - GRID_HEPE - GRID_DINV) * 32;
        const float* sbase = node + row0 * FIN;
        float* dbase = nodeW + row0 * FIN;
#pragma unroll
        for (int k = 0; k < 16; k++) {
            int idx = k * 256 + t;
            tile[idx >> 7][idx & 127] = sbase[idx];
        }
        __syncthreads();
        int f = t & 127;
        int h = t >> 7;
        float acc[16];
#pragma unroll
        for (int j = 0; j < 16; j++) acc[j] = 0.f;
        for (int k = 0; k < 128; k += 2) {
            float w0 = W[k * 128 + f];
            float w1 = W[(k + 1) * 128 + f];
#pragma unroll
            for (int j = 0; j < 16; j++) {
                float2 tv = *(const float2*)&tile[h * 16 + j][k];
                acc[j] += tv.x * w0 + tv.y * w1;
            }
        }
#pragma unroll
        for (int j = 0; j < 16; j++) dbase[(size_t)(h * 16 + j) * 128 + f] = acc[j];
    }
}

// ---------------- K_gemm (fallback epilogue, in-place) ----------------
__global__ __launch_bounds__(256) void k_gemm(const float* __restrict__ src,
                                              const float* __restrict__ W,
                                              float* __restrict__ dst) {
    __shared__ float tile[32][FIN];
    int t = threadIdx.x;
    size_t row0 = (size_t)blockIdx.x * 32;
    const float* sbase = src + row0 * FIN;
    float* dbase = dst + row0 * FIN;
#pragma unroll
    for (int k = 0; k < 16; k++) {
        int idx = k * 256 + t;
        tile[idx >> 7][idx & 127] = sbase[idx];
    }
    __syncthreads();
    int f = t & 127;
    int h = t >> 7;
    float acc[16];
#pragma unroll
    for (int j = 0; j < 16; j++) acc[j] = 0.f;
    for (int k = 0; k < 128; k += 2) {
        float w0 = W[k * 128 + f];
        float w1 = W[(k + 1) * 128 + f];
#pragma unroll
        for (int j = 0; j < 16; j++) {
            float2 tv = *(const float2*)&tile[h * 16 + j][k];
            acc[j] += tv.x * w0 + tv.y * w1;
        }
    }
#pragma unroll
    for (int j = 0; j < 16; j++) dbase[(size_t)(h * 16 + j) * 128 + f] = acc[j];
}

// ---------------- K_main: out[b,n,:] = sum over (e in edges(n), m in nodes(e)) of
//                      h[e] * (A[n,m]+delta_nm) * dinv[m] * rows[m,:]  ----------------
__global__ __launch_bounds__(256) void k_main(const float* __restrict__ A,
                                              const float* __restrict__ rows,
                                              const float* __restrict__ hepe,
                                              const float* __restrict__ dinv,
                                              const u16* __restrict__ lists,
                                              const int* __restrict__ ecnt,
                                              const u16* __restrict__ elists,
                                              float* __restrict__ out) {
    int lane = threadIdx.x & 63;
    int wid  = threadIdx.x >> 6;
    int row  = blockIdx.x * 4 + wid;            // b*N + n
    int b = row >> 12, n = row & (NN - 1);

    const u16* L = lists + (size_t)row * LSTRIDE;
    int cn = L[0];
    int eReg = 0; float hReg = 0.f;
    if (lane < cn) {
        eReg = L[1 + lane];
        hReg = hepe[(b << 10) + eReg];
    }

    const float2* rows2 = (const float2*)rows;
    float2 acc = make_float2(0.f, 0.f);

    for (int j = 0; j < cn; j++) {
        int   e = __shfl(eReg, j, 64);
        float h = __shfl(hReg, j, 64);
        int eb = (b << 10) + e;
        int cm = ecnt[eb];
        if (cm > CAPE) cm = CAPE;
        float c = 0.f; int m = 0;
        if (lane < cm) {
            m = elists[(size_t)eb * CAPE + lane];
            float a = A[((size_t)b << 24) + ((size_t)n << 12) + m];
            if (m == n) a += 1.0f;              // A = node_adj + I
            if (a != 0.f) c = h * a * dinv[(b << 12) + m];
        }
        u64 mask = __ballot(c != 0.f);
        while (mask) {
            int src = __ffsll(mask) - 1;
            mask &= mask - 1;
            float cb = __shfl(c, src, 64);
            int   mb = __shfl(m, src, 64);
            float2 nv = rows2[((size_t)((b << 12) + mb)) * 64 + lane];
            acc.x += cb * nv.x;
            acc.y += cb * nv.y;
        }
    }
    float2* out2 = (float2*)out;
    out2[(size_t)row * 64 + lane] = acc;
}

extern "C" void kernel_launch(void* const* d_in, const int* in_sizes, int n_in,
                              void* d_out, int out_size, void* d_ws, size_t ws_size,
                              hipStream_t stream) {
    const float* node     = (const float*)d_in[0];
    const float* edge     = (const float*)d_in[1];
    const float* node_adj = (const float*)d_in[2];
    const float* D        = (const float*)d_in[3];
    const float* T        = (const float*)d_in[4];
    const float* ew       = (const float*)d_in[5];
    const float* W        = (const float*)d_in[6];
    float* out = (float*)d_out;

    // workspace layout
    char* ws = (char*)d_ws;
    float* hepe  = (float*)ws;                          ws += BB * EE * 4;          // 16 KB
    float* dinv  = (float*)ws;                          ws += BB * NN * 4;          // 64 KB
    int*   ecnt  = (int*)ws;                            ws += BB * EE * 4;          // 16 KB
    u16*   lists = (u16*)ws;                            ws += BB * NN * LSTRIDE * 2;// ~1.1 MB
    u16*   elists= (u16*)ws;                            ws += BB * EE * CAPE * 2;   // 320 KB
    size_t small_need = (size_t)(ws - (char*)d_ws);
    float* nodeW = (float*)ws;                          // 8.39 MB (optional)
    bool fuse = ws_size >= small_need + (size_t)BB * NN * FIN * 4;

    hipMemsetAsync(ecnt, 0, BB * EE * 4, stream);

    int grid = GRID_LISTS + GRID_HEPE + GRID_DINV + (fuse ? GRID_GEMM : 0);
    k_pre<<<grid, 256, 0, stream>>>(T, edge, ew, D, node, W,
                                    hepe, dinv, lists, ecnt, elists, nodeW,
                                    fuse ? 1 : 0);

    if (fuse) {
        k_main<<<BB * NN / 4, 256, 0, stream>>>(node_adj, nodeW, hepe, dinv,
                                                lists, ecnt, elists, out);
    } else {
        k_main<<<BB * NN / 4, 256, 0, stream>>>(node_adj, node, hepe, dinv,
                                                lists, ecnt, elists, out);
        k_gemm<<<BB * NN / 32, 256, 0, stream>>>(out, W, out);
    }
}